// Round 3
// baseline (659.401 us; speedup 1.0000x reference)
//
#include <hip/hip_runtime.h>

typedef __attribute__((ext_vector_type(4))) float f32x4;
typedef __attribute__((ext_vector_type(8))) short short8;
typedef __attribute__((ext_vector_type(4))) short short4v;

#define MFMA_B16(a,b,c) __builtin_amdgcn_mfma_f32_16x16x32_bf16((a),(b),(c),0,0,0)

static __device__ __forceinline__ unsigned short f2bf(float x){
  unsigned int u = __float_as_uint(x);
  u += 0x7fffu + ((u >> 16) & 1u);
  return (unsigned short)(u >> 16);
}

static __device__ __forceinline__ short8 pack8(f32x4 a, f32x4 b){
  short8 r;
  r[0]=(short)f2bf(a[0]); r[1]=(short)f2bf(a[1]); r[2]=(short)f2bf(a[2]); r[3]=(short)f2bf(a[3]);
  r[4]=(short)f2bf(b[0]); r[5]=(short)f2bf(b[1]); r[6]=(short)f2bf(b[2]); r[7]=(short)f2bf(b[3]);
  return r;
}

// C-layout 16x16 tile X[row=4q+r][col=c] -> A/B-frag of X^T orientation:
// frag[j] = X[row=q*8+j][col=c]; src lane = 16*(2q + (j>>2)) + c, src reg j&3.
// Valid for target quads 0,1 (k<16); caller zeroes quads 2,3.
static __device__ __forceinline__ short8 xpose(const f32x4& X, int lane){
  const int c = lane & 15, q = lane >> 4;
  const int s0 = (q*32 + c) & 63, s1 = (q*32 + 16 + c) & 63;
  f32x4 lo, hi;
  #pragma unroll
  for (int r = 0; r < 4; ++r){ lo[r] = __shfl(X[r], s0); hi[r] = __shfl(X[r], s1); }
  return pack8(lo, hi);
}

__global__ void prep_w(const float* __restrict__ ipw, const float* __restrict__ opw,
                       unsigned short* __restrict__ wbf){
  int i = blockIdx.x * 256 + threadIdx.x;
  float v = (i < 384*128) ? ipw[i] : opw[i - 384*128];
  wbf[i] = f2bf(v);
}

#define STR 136   // shorts per staged row (128 + 8 pad)

// Head-per-wave fused window attention (2 heads/wave, 4 waves).
// Templated on max tile count TTP: group1 (L=36) -> TTP=3, group2 (L=100) -> TTP=7.
// V-projection A-frags are gathered DIRECTLY from global feat (no sF staging);
// the O buffer reuses the sQK region after the post-projection barrier.
// LDS: sQK[16*TTP][STR] + 4 per-wave P strips [16][PSTR], PSTR = 16*(TTP+1)+8.
// TTP=7: 47872 B -> 3 blocks/CU.  TTP=3: 22272 B -> 5-7 blocks/CU (VGPR-capped).
template<int TTP>
__global__ __launch_bounds__(256, 2)
void fused_attn(const float* __restrict__ feat,
                const float* __restrict__ pos,
                const int* __restrict__ inds,
                int LW,
                const unsigned short* __restrict__ wqkv,   // bf16 [384][128]
                const unsigned short* __restrict__ wout,   // bf16 [128][128]
                const float* __restrict__ ipb, const float* __restrict__ opb,
                float* __restrict__ out)
{
  constexpr int PSTR = 16*(TTP+1) + 8;   // P-strip row length (keys + tail + pad)
  extern __shared__ __align__(16) unsigned short smem[];
  unsigned short* sQK = smem;                     // [16*TTP][STR] bf16 (f+pos); O buffer later
  unsigned short* sPb = smem + 16*TTP*STR;        // per-wave [16][PSTR] P strips

  const int w = blockIdx.x;
  const int Lv = (w & 1) ? (LW >> 1) : LW;
  const int T  = (Lv + 15) >> 4;              // query/key tiles (<= TTP)
  const long ibase = (long)w * LW;
  const int tid = threadIdx.x;
  const int wv = tid >> 6, lane = tid & 63, c = lane & 15, q = lane >> 4;
  const short8 Z8 = {0,0,0,0,0,0,0,0};
  const f32x4  Z4 = {0.f,0.f,0.f,0.f};

  // ---- stage qk=f+pos as bf16 (zero invalid rows); 16 rows x 16 chunks per sweep
  {
    const int rg = tid >> 4, ch = tid & 15;
    #pragma unroll
    for (int s = 0; s < TTP; ++s){
      if (s < T){
        const int row = s*16 + rg;
        short8 qv = Z8;
        if (row < Lv){
          const int tok = inds[ibase + row];
          const float* fr = feat + (long)tok*128 + ch*8;
          const float* pr = pos + (ibase + row)*128 + ch*8;
          f32x4 f0 = *(const f32x4*)fr, f1 = *(const f32x4*)(fr+4);
          f32x4 p0 = *(const f32x4*)pr, p1 = *(const f32x4*)(pr+4);
          qv = pack8(f0+p0, f1+p1);
        }
        *(short8*)&sQK[row*STR + ch*8] = qv;
      }
    }
  }
  __syncthreads();

  unsigned short* Pb = sPb + wv*16*PSTR;
  // Zero the P-strip tail key block [16T, 16T+16) when T is odd: the PV
  // A-frag reads 32-key groups, so the last group covers tile T which is
  // never written. Uninitialized LDS there can decode as bf16 NaN, and
  // NaN * 0 (the zeroed V tail) = NaN in valid rows.
  if (T & 1){
    #pragma unroll
    for (int r = 0; r < 4; ++r)
      Pb[(4*q + r)*PSTR + 16*T + c] = 0;
  }
  short4v of[2][TTP];          // per-head O tiles, bf16-packed C-layout rows

  #pragma unroll
  for (int hh = 0; hh < 2; ++hh){
    const int h = wv*2 + hh;
    // W fragments: lane(q,c) holds W[h*16+c][q*8+j (+32kk)] — serves as
    // B-frag (x @ W^T) AND as A-frag (W @ x^T) simultaneously.
    short8 bQ[4], bK[4], bV[4];
    const unsigned short* wr = wqkv + (h*16 + c)*128 + q*8;
    #pragma unroll
    for (int kk = 0; kk < 4; ++kk){
      bQ[kk] = *(const short8*)(wr + kk*32);
      bK[kk] = *(const short8*)(wr + kk*32 + 128*128);
      bV[kk] = *(const short8*)(wr + kk*32 + 2*128*128);
    }
    float bq_r[4], bk_r[4];
    #pragma unroll
    for (int r = 0; r < 4; ++r){
      bq_r[r] = ipb[h*16 + 4*q + r];          // Q^T C-tile row = hd = 4q+r
      bk_r[r] = ipb[128 + h*16 + 4*q + r];
    }
    const float bv_c = ipb[256 + h*16 + c];   // V C-tile col = hd = c

    short8 qAf[TTP], kBf[TTP];
    f32x4 va[TTP];
    #pragma unroll
    for (int t = 0; t < TTP; ++t) va[t] = Z4;  // tiles >= T must be zero (PV tail)

    #pragma unroll
    for (int t = 0; t < TTP; ++t) if (t < T){
      // V A-frag row for this lane: token row 16t+c, cols kk*32 + q*8 .. +7
      const int vrow = 16*t + c;
      const float* frow = (vrow < Lv) ? (feat + (long)inds[ibase + vrow]*128) : nullptr;
      f32x4 qt = Z4, kt = Z4, vt = Z4;
      #pragma unroll
      for (int kk = 0; kk < 4; ++kk){
        const short8 aQ = *(const short8*)&sQK[(16*t + c)*STR + kk*32 + q*8];
        short8 aF = Z8;
        if (frow){
          const float* fp = frow + kk*32 + q*8;
          aF = pack8(*(const f32x4*)fp, *(const f32x4*)(fp+4));
        }
        qt = MFMA_B16(bQ[kk], aQ, qt);        // C [hd][query]  (Q^T)
        kt = MFMA_B16(bK[kk], aQ, kt);        // C [hd][key]    (K^T)
        vt = MFMA_B16(aF, bV[kk], vt);        // C [key][hd]
      }
      #pragma unroll
      for (int r = 0; r < 4; ++r){
        qt[r] = (qt[r] + bq_r[r]) * 0.25f;    // fold 1/sqrt(HD)
        kt[r] += bk_r[r];
        const int key = 16*t + 4*q + r;
        vt[r] = (key < Lv) ? (vt[r] + bv_c) : 0.f;  // zero padded keys (bias!)
      }
      short8 tq8 = xpose(qt, lane);
      qAf[t] = (q < 2) ? tq8 : Z8;            // A[m=query][k=hd], k<16 padded
      short8 tk8 = xpose(kt, lane);
      kBf[t] = (q < 2) ? tk8 : Z8;            // B[k=hd][n=key]
      va[t] = vt;
    }

    // V B-frags: B[k=key32][n=hd]; quads 0,1 <- tile 2u, quads 2,3 <- tile 2u+1
    short8 vBf[(TTP+1)/2];
    #pragma unroll
    for (int u = 0; u < (TTP+1)/2; ++u) if (u < ((T+1)>>1)){
      const int s0 = 32*(q & 1) + c, s1 = s0 + 16;
      f32x4 A0 = va[2*u];
      f32x4 A1 = (2*u+1 < TTP) ? va[2*u+1] : Z4;
      f32x4 lo, hi;
      #pragma unroll
      for (int r = 0; r < 4; ++r){
        float a0 = __shfl(A0[r], s0), a1 = __shfl(A1[r], s0);
        lo[r] = (q < 2) ? a0 : a1;
        float b0 = __shfl(A0[r], s1), b1 = __shfl(A1[r], s1);
        hi[r] = (q < 2) ? b0 : b1;
      }
      vBf[u] = pack8(lo, hi);
    }

    // ---- per query tile: scores, softmax, PV (no barriers; per-wave LDS strip)
    #pragma unroll
    for (int t = 0; t < TTP; ++t) if (t < T){
      f32x4 S[TTP];
      #pragma unroll
      for (int tk = 0; tk < TTP; ++tk) if (tk < T){
        S[tk] = MFMA_B16(qAf[t], kBf[tk], Z4);      // C [query][key]
        if (16*tk + c >= Lv){
          S[tk][0] = -1e30f; S[tk][1] = -1e30f; S[tk][2] = -1e30f; S[tk][3] = -1e30f;
        }
      }
      f32x4 inv;
      #pragma unroll
      for (int r = 0; r < 4; ++r){
        float m = -1e30f;
        #pragma unroll
        for (int tk = 0; tk < TTP; ++tk) if (tk < T) m = fmaxf(m, S[tk][r]);
        m = fmaxf(m, __shfl_xor(m, 1));
        m = fmaxf(m, __shfl_xor(m, 2));
        m = fmaxf(m, __shfl_xor(m, 4));
        m = fmaxf(m, __shfl_xor(m, 8));
        float sum = 0.f;
        #pragma unroll
        for (int tk = 0; tk < TTP; ++tk) if (tk < T){
          float e = __expf(S[tk][r] - m);
          S[tk][r] = e; sum += e;
        }
        sum += __shfl_xor(sum, 1);
        sum += __shfl_xor(sum, 2);
        sum += __shfl_xor(sum, 4);
        sum += __shfl_xor(sum, 8);
        inv[r] = 1.0f / sum;
      }
      // write unnormalized P strip (same-wave LDS: in-order, no barrier)
      #pragma unroll
      for (int tk = 0; tk < TTP; ++tk) if (tk < T){
        #pragma unroll
        for (int r = 0; r < 4; ++r)
          Pb[(4*q + r)*PSTR + 16*tk + c] = f2bf(S[tk][r]);
      }
      f32x4 o = Z4;
      #pragma unroll
      for (int u = 0; u < (TTP+1)/2; ++u) if (u < ((T+1)>>1)){
        const short8 ap = *(const short8*)&Pb[c*PSTR + 32*u + q*8];  // A[m=query][k=key]
        o = MFMA_B16(ap, vBf[u], o);                                 // C [query][hd]
      }
      short4v ob;
      #pragma unroll
      for (int r = 0; r < 4; ++r) ob[r] = (short)f2bf(o[r] * inv[r]);
      of[hh][t] = ob;
    }
  } // hh

  __syncthreads();   // all waves done reading sQK; region becomes O buffer
  #pragma unroll
  for (int hh = 0; hh < 2; ++hh){
    const int h = wv*2 + hh;
    #pragma unroll
    for (int t = 0; t < TTP; ++t) if (t < T){
      #pragma unroll
      for (int r = 0; r < 4; ++r)
        sQK[(16*t + 4*q + r)*STR + h*16 + c] = (unsigned short)of[hh][t][r];
    }
  }
  __syncthreads();   // O complete

  // ---- out projection: wave handles query tiles {wv, wv+4}
  float bo_r[8];
  #pragma unroll
  for (int ct = 0; ct < 8; ++ct) bo_r[ct] = opb[ct*16 + c];
  #pragma unroll
  for (int ti = 0; ti < 2; ++ti){
    const int t = wv + ti*4;
    if (t < T){
      f32x4 acc[8];
      #pragma unroll
      for (int ct = 0; ct < 8; ++ct) acc[ct] = Z4;
      #pragma unroll
      for (int p = 0; p < 4; ++p){
        const short8 ao = *(const short8*)&sQK[(16*t + c)*STR + p*32 + q*8];
        #pragma unroll
        for (int ct = 0; ct < 8; ++ct){
          const short8 bw = *(const short8*)&wout[(ct*16 + c)*128 + p*32 + q*8];
          acc[ct] = MFMA_B16(ao, bw, acc[ct]);
        }
      }
      #pragma unroll
      for (int r = 0; r < 4; ++r){
        const int l = 16*t + 4*q + r;
        if (l < Lv){
          const int tok = inds[ibase + l];
          float* orow = out + (long)tok*128;
          #pragma unroll
          for (int ct = 0; ct < 8; ++ct)
            orow[ct*16 + c] = acc[ct][r] + bo_r[ct];
        }
      }
    }
  }
}

extern "C" void kernel_launch(void* const* d_in, const int* in_sizes, int n_in,
                              void* d_out, int out_size, void* d_ws, size_t ws_size,
                              hipStream_t stream) {
  const float* feat = (const float*)d_in[0];
  const float* pos1 = (const float*)d_in[1];
  const float* pos2 = (const float*)d_in[2];
  const float* ipw  = (const float*)d_in[3];
  const float* ipb  = (const float*)d_in[4];
  const float* opw  = (const float*)d_in[5];
  const float* opb  = (const float*)d_in[6];
  const int*   inds1 = (const int*)d_in[7];
  const int*   inds2 = (const int*)d_in[8];
  float* out = (float*)d_out;
  unsigned short* wbf = (unsigned short*)d_ws;   // 384*128 + 128*128 bf16
  unsigned short* wob = wbf + 384*128;

  prep_w<<<dim3(256), dim3(256), 0, stream>>>(ipw, opw, wbf);

  // group2 (L=100): TTP=7. LDS = (112*136 + 64*136)*2 = 47872 B -> 3 blocks/CU
  {
    const int lds2 = (16*7*STR + 4*16*(16*8 + 8)) * 2;
    hipFuncSetAttribute((const void*)fused_attn<7>,
                        hipFuncAttributeMaxDynamicSharedMemorySize, lds2);
    fused_attn<7><<<dim3(1024), dim3(256), lds2, stream>>>(
        feat, pos2, inds2, 100, wbf, wob, ipb, opb, out);
  }
  // group1 (L=36): TTP=3. LDS = (48*136 + 64*72)*2 = 22272 B -> 5-7 blocks/CU
  {
    const int lds1 = (16*3*STR + 4*16*(16*4 + 8)) * 2;
    hipFuncSetAttribute((const void*)fused_attn<3>,
                        hipFuncAttributeMaxDynamicSharedMemorySize, lds1);
    fused_attn<3><<<dim3(4096), dim3(256), lds1, stream>>>(
        feat, pos1, inds1, 36, wbf, wob, ipb, opb, out);
  }
}

// Round 5
// 481.693 us; speedup vs baseline: 1.3689x; 1.3689x over previous
//
#include <hip/hip_runtime.h>

typedef __attribute__((ext_vector_type(4))) float f32x4;
typedef __attribute__((ext_vector_type(8))) short short8;
typedef __attribute__((ext_vector_type(4))) short short4v;

#define MFMA_B16(a,b,c) __builtin_amdgcn_mfma_f32_16x16x32_bf16((a),(b),(c),0,0,0)

static __device__ __forceinline__ unsigned short f2bf(float x){
  unsigned int u = __float_as_uint(x);
  u += 0x7fffu + ((u >> 16) & 1u);
  return (unsigned short)(u >> 16);
}

static __device__ __forceinline__ short8 pack8(f32x4 a, f32x4 b){
  short8 r;
  r[0]=(short)f2bf(a[0]); r[1]=(short)f2bf(a[1]); r[2]=(short)f2bf(a[2]); r[3]=(short)f2bf(a[3]);
  r[4]=(short)f2bf(b[0]); r[5]=(short)f2bf(b[1]); r[6]=(short)f2bf(b[2]); r[7]=(short)f2bf(b[3]);
  return r;
}

// C-layout 16x16 tile X[row=4q+r][col=c] -> A/B-frag of X^T orientation:
// frag[j] = X[row=q*8+j][col=c]; src lane = 16*(2q + (j>>2)) + c, src reg j&3.
// Valid for target quads 0,1 (k<16); caller zeroes quads 2,3.
static __device__ __forceinline__ short8 xpose(const f32x4& X, int lane){
  const int c = lane & 15, q = lane >> 4;
  const int s0 = (q*32 + c) & 63, s1 = (q*32 + 16 + c) & 63;
  f32x4 lo, hi;
  #pragma unroll
  for (int r = 0; r < 4; ++r){ lo[r] = __shfl(X[r], s0); hi[r] = __shfl(X[r], s1); }
  return pack8(lo, hi);
}

__global__ void prep_w(const float* __restrict__ ipw, const float* __restrict__ opw,
                       unsigned short* __restrict__ wbf){
  int i = blockIdx.x * 256 + threadIdx.x;
  float v = (i < 384*128) ? ipw[i] : opw[i - 384*128];
  wbf[i] = f2bf(v);
}

#define STR 136   // shorts per staged row (128 + 8 pad)

// Head-per-wave fused window attention (2 heads/wave, 4 waves).
// Templated on max tile count TTP: group1 (L=36) -> TTP=3, group2 (L=100) -> TTP=7.
// Scores computed as S^T = MFMA(K-frag, Q-frag): key-softmax is per-lane
// (28 in-register values + 2 shuffle hops) instead of 4-hop cross-lane x4 rows.
// P normalized in-register, written as one b64 per (lane, key-tile).
template<int TTP>
__global__ __launch_bounds__(256, 2)
void fused_attn(const float* __restrict__ feat,
                const float* __restrict__ pos,
                const int* __restrict__ inds,
                int LW,
                const unsigned short* __restrict__ wqkv,   // bf16 [384][128]
                const unsigned short* __restrict__ wout,   // bf16 [128][128]
                const float* __restrict__ ipb, const float* __restrict__ opb,
                float* __restrict__ out)
{
  constexpr int PSTR = 16*(TTP+1) + 8;   // P-strip row length (keys + tail + pad)
  extern __shared__ __align__(16) unsigned short smem[];
  unsigned short* sQK = smem;                     // [16*TTP][STR] bf16 (f+pos)
  unsigned short* sF  = smem + 16*TTP*STR;        // [16*TTP][STR] bf16 f, reused for O
  unsigned short* sPb = smem + 2*16*TTP*STR;      // per-wave [16][PSTR] P strips

  const int w = blockIdx.x;
  const int Lv = (w & 1) ? (LW >> 1) : LW;
  const int T  = (Lv + 15) >> 4;              // query/key tiles (<= TTP)
  const long ibase = (long)w * LW;
  const int tid = threadIdx.x;
  const int wv = tid >> 6, lane = tid & 63, c = lane & 15, q = lane >> 4;
  const short8 Z8 = {0,0,0,0,0,0,0,0};
  const f32x4  Z4 = {0.f,0.f,0.f,0.f};

  // ---- stage f and qk=f+pos as bf16 (zero invalid rows); 16 rows x 16 chunks per sweep
  {
    const int rg = tid >> 4, ch = tid & 15;
    #pragma unroll
    for (int s = 0; s < TTP; ++s){
      if (s < T){
        const int row = s*16 + rg;
        short8 fv = Z8, qv = Z8;
        if (row < Lv){
          const int tok = inds[ibase + row];
          const float* fr = feat + (long)tok*128 + ch*8;
          const float* pr = pos + (ibase + row)*128 + ch*8;
          f32x4 f0 = *(const f32x4*)fr, f1 = *(const f32x4*)(fr+4);
          f32x4 p0 = *(const f32x4*)pr, p1 = *(const f32x4*)(pr+4);
          fv = pack8(f0, f1); qv = pack8(f0+p0, f1+p1);
        }
        *(short8*)&sF [row*STR + ch*8] = fv;
        *(short8*)&sQK[row*STR + ch*8] = qv;
      }
    }
  }
  __syncthreads();

  unsigned short* Pb = sPb + wv*16*PSTR;
  // Zero the P-strip tail key block [16T, 16T+16) when T is odd: the PV
  // A-frag reads 32-key groups, so the last group covers tile T which is
  // never written. Uninitialized LDS there can decode as bf16 NaN, and
  // NaN * 0 (the zeroed V tail) = NaN in valid rows.
  if (T & 1){
    const short4v z4 = {0,0,0,0};
    *(short4v*)&Pb[c*PSTR + 16*T + 4*q] = z4;
  }
  short4v of[2][TTP];          // per-head O tiles, bf16-packed C-layout rows

  #pragma unroll
  for (int hh = 0; hh < 2; ++hh){
    const int h = wv*2 + hh;
    // W fragments: lane(q,c) holds W[h*16+c][q*8+j (+32kk)] — serves as
    // B-frag (x @ W^T) AND as A-frag (W @ x^T) simultaneously.
    short8 bQ[4], bK[4], bV[4];
    const unsigned short* wr = wqkv + (h*16 + c)*128 + q*8;
    #pragma unroll
    for (int kk = 0; kk < 4; ++kk){
      bQ[kk] = *(const short8*)(wr + kk*32);
      bK[kk] = *(const short8*)(wr + kk*32 + 128*128);
      bV[kk] = *(const short8*)(wr + kk*32 + 2*128*128);
    }
    float bq_r[4], bk_r[4];
    #pragma unroll
    for (int r = 0; r < 4; ++r){
      bq_r[r] = ipb[h*16 + 4*q + r];          // Q^T C-tile row = hd = 4q+r
      bk_r[r] = ipb[128 + h*16 + 4*q + r];
    }
    const float bv_c = ipb[256 + h*16 + c];   // V C-tile col = hd = c

    short8 qAf[TTP], kBf[TTP];
    f32x4 va[TTP];
    #pragma unroll
    for (int t = 0; t < TTP; ++t) va[t] = Z4;  // tiles >= T must be zero (PV tail)

    #pragma unroll
    for (int t = 0; t < TTP; ++t) if (t < T){
      f32x4 qt = Z4, kt = Z4, vt = Z4;
      #pragma unroll
      for (int kk = 0; kk < 4; ++kk){
        const short8 aQ = *(const short8*)&sQK[(16*t + c)*STR + kk*32 + q*8];
        const short8 aF = *(const short8*)&sF [(16*t + c)*STR + kk*32 + q*8];
        qt = MFMA_B16(bQ[kk], aQ, qt);        // C [hd][query]  (Q^T)
        kt = MFMA_B16(bK[kk], aQ, kt);        // C [hd][key]    (K^T)
        vt = MFMA_B16(aF, bV[kk], vt);        // C [key][hd]
      }
      #pragma unroll
      for (int r = 0; r < 4; ++r){
        qt[r] = (qt[r] + bq_r[r]) * 0.25f;    // fold 1/sqrt(HD)
        kt[r] += bk_r[r];
        const int key = 16*t + 4*q + r;
        vt[r] = (key < Lv) ? (vt[r] + bv_c) : 0.f;  // zero padded keys (bias!)
      }
      short8 tq8 = xpose(qt, lane);
      qAf[t] = (q < 2) ? tq8 : Z8;            // A[m=query][k=hd], k<16 padded
      short8 tk8 = xpose(kt, lane);
      kBf[t] = (q < 2) ? tk8 : Z8;            // B[k=hd][n=key]
      va[t] = vt;
    }

    // V B-frags: B[k=key32][n=hd]; quads 0,1 <- tile 2u, quads 2,3 <- tile 2u+1
    short8 vBf[(TTP+1)/2];
    #pragma unroll
    for (int u = 0; u < (TTP+1)/2; ++u) if (u < ((T+1)>>1)){
      const int s0 = 32*(q & 1) + c, s1 = s0 + 16;
      f32x4 A0 = va[2*u];
      f32x4 A1 = (2*u+1 < TTP) ? va[2*u+1] : Z4;
      f32x4 lo, hi;
      #pragma unroll
      for (int r = 0; r < 4; ++r){
        float a0 = __shfl(A0[r], s0), a1 = __shfl(A1[r], s0);
        lo[r] = (q < 2) ? a0 : a1;
        float b0 = __shfl(A0[r], s1), b1 = __shfl(A1[r], s1);
        hi[r] = (q < 2) ? b0 : b1;
      }
      vBf[u] = pack8(lo, hi);
    }

    // ---- per query tile: S^T scores, per-lane softmax, PV (no barriers)
    #pragma unroll
    for (int t = 0; t < TTP; ++t) if (t < T){
      f32x4 St[TTP];
      #pragma unroll
      for (int tk = 0; tk < TTP; ++tk) if (tk < T){
        St[tk] = MFMA_B16(kBf[tk], qAf[t], Z4);     // C [key][query] = S^T
        #pragma unroll
        for (int r = 0; r < 4; ++r){
          const int key = 16*tk + 4*q + r;
          if (key >= Lv) St[tk][r] = -1e30f;        // mask padded keys
        }
      }
      // softmax for query = c (per-lane): keys live in 4 regs x T tiles x 4 q-groups
      f32x4 mm = {-1e30f,-1e30f,-1e30f,-1e30f};
      #pragma unroll
      for (int tk = 0; tk < TTP; ++tk) if (tk < T){
        mm[0]=fmaxf(mm[0],St[tk][0]); mm[1]=fmaxf(mm[1],St[tk][1]);
        mm[2]=fmaxf(mm[2],St[tk][2]); mm[3]=fmaxf(mm[3],St[tk][3]);
      }
      float m = fmaxf(fmaxf(mm[0],mm[1]), fmaxf(mm[2],mm[3]));
      m = fmaxf(m, __shfl_xor(m, 16));
      m = fmaxf(m, __shfl_xor(m, 32));
      f32x4 ss = Z4;
      #pragma unroll
      for (int tk = 0; tk < TTP; ++tk) if (tk < T){
        #pragma unroll
        for (int r = 0; r < 4; ++r){
          float e = __expf(St[tk][r] - m);
          St[tk][r] = e; ss[r] += e;
        }
      }
      float sum = (ss[0]+ss[1]) + (ss[2]+ss[3]);
      sum += __shfl_xor(sum, 16);
      sum += __shfl_xor(sum, 32);
      const float inv = 1.0f / sum;
      // write normalized P strip: row = query c, 4 consecutive keys per lane (b64)
      #pragma unroll
      for (int tk = 0; tk < TTP; ++tk) if (tk < T){
        short4v p4;
        #pragma unroll
        for (int r = 0; r < 4; ++r) p4[r] = (short)f2bf(St[tk][r] * inv);
        *(short4v*)&Pb[c*PSTR + 16*tk + 4*q] = p4;
      }
      f32x4 o = Z4;
      #pragma unroll
      for (int u = 0; u < (TTP+1)/2; ++u) if (u < ((T+1)>>1)){
        const short8 ap = *(const short8*)&Pb[c*PSTR + 32*u + q*8];  // A[m=query][k=key]
        o = MFMA_B16(ap, vBf[u], o);                                 // C [query][hd]
      }
      short4v ob;
      #pragma unroll
      for (int r = 0; r < 4; ++r) ob[r] = (short)f2bf(o[r]);
      of[hh][t] = ob;
    }
  } // hh

  __syncthreads();   // all waves done reading sF/sQK
  #pragma unroll
  for (int hh = 0; hh < 2; ++hh){
    const int h = wv*2 + hh;
    #pragma unroll
    for (int t = 0; t < TTP; ++t) if (t < T){
      #pragma unroll
      for (int r = 0; r < 4; ++r)
        sF[(16*t + 4*q + r)*STR + h*16 + c] = (unsigned short)of[hh][t][r];
    }
  }
  __syncthreads();   // O complete

  // ---- out projection: wave handles query tiles {wv, wv+4}
  float bo_r[8];
  #pragma unroll
  for (int ct = 0; ct < 8; ++ct) bo_r[ct] = opb[ct*16 + c];
  #pragma unroll
  for (int ti = 0; ti < 2; ++ti){
    const int t = wv + ti*4;
    if (t < T){
      f32x4 acc[8];
      #pragma unroll
      for (int ct = 0; ct < 8; ++ct) acc[ct] = Z4;
      #pragma unroll
      for (int p = 0; p < 4; ++p){
        const short8 ao = *(const short8*)&sF[(16*t + c)*STR + p*32 + q*8];
        #pragma unroll
        for (int ct = 0; ct < 8; ++ct){
          const short8 bw = *(const short8*)&wout[(ct*16 + c)*128 + p*32 + q*8];
          acc[ct] = MFMA_B16(ao, bw, acc[ct]);
        }
      }
      #pragma unroll
      for (int r = 0; r < 4; ++r){
        const int l = 16*t + 4*q + r;
        if (l < Lv){
          const int tok = inds[ibase + l];
          float* orow = out + (long)tok*128;
          #pragma unroll
          for (int ct = 0; ct < 8; ++ct)
            orow[ct*16 + c] = acc[ct][r] + bo_r[ct];
        }
      }
    }
  }
}

extern "C" void kernel_launch(void* const* d_in, const int* in_sizes, int n_in,
                              void* d_out, int out_size, void* d_ws, size_t ws_size,
                              hipStream_t stream) {
  const float* feat = (const float*)d_in[0];
  const float* pos1 = (const float*)d_in[1];
  const float* pos2 = (const float*)d_in[2];
  const float* ipw  = (const float*)d_in[3];
  const float* ipb  = (const float*)d_in[4];
  const float* opw  = (const float*)d_in[5];
  const float* opb  = (const float*)d_in[6];
  const int*   inds1 = (const int*)d_in[7];
  const int*   inds2 = (const int*)d_in[8];
  float* out = (float*)d_out;
  unsigned short* wbf = (unsigned short*)d_ws;   // 384*128 + 128*128 bf16
  unsigned short* wob = wbf + 384*128;

  prep_w<<<dim3(256), dim3(256), 0, stream>>>(ipw, opw, wbf);

  // group2 (L=100): TTP=7. LDS = (2*112*136 + 4*16*136)*2 = 78336 B -> 2 blocks/CU
  {
    const int lds2 = (2*112*STR + 4*16*(16*8 + 8)) * 2;
    hipFuncSetAttribute((const void*)fused_attn<7>,
                        hipFuncAttributeMaxDynamicSharedMemorySize, lds2);
    fused_attn<7><<<dim3(1024), dim3(256), lds2, stream>>>(
        feat, pos2, inds2, 100, wbf, wob, ipb, opb, out);
  }
  // group1 (L=36): TTP=3. LDS = (2*48*136 + 4*16*72)*2 = 35328 B -> 4 blocks/CU
  {
    const int lds1 = (2*48*STR + 4*16*(16*4 + 8)) * 2;
    hipFuncSetAttribute((const void*)fused_attn<3>,
                        hipFuncAttributeMaxDynamicSharedMemorySize, lds1);
    fused_attn<3><<<dim3(4096), dim3(256), lds1, stream>>>(
        feat, pos1, inds1, 36, wbf, wob, ipb, opb, out);
  }
}